// Round 17
// baseline (2496.609 us; speedup 1.0000x reference)
//
#include <hip/hip_runtime.h>
#include <math.h>

// Force numpy-style arithmetic: no FMA contraction, no reassociation.
// RF kernels use explicit fmaf() where fusion is wanted (smooth ops).
#pragma clang fp contract(off)
#pragma clang fp reassociate(off)

#define NU 100000
#define NI 50000
#define NT 150000
#define DD 64
#define NE 2000000
#define NTD (NT * DD)

// Endpoint-balanced bucketed CSR build: 50 user buckets x 2000 users + 50 item
// buckets x 1000 items = ~40K endpoints/bucket either way; 8 class sub-arrays each.
// Per (bucket,class): ~5000 +- 70 records. SUBCAP=8192 is a 45-sigma margin.
// (r16 crash: single 1875-node bucket width gave item buckets 9375/class > 8192.)
#define NBUCK 100
#define BW_U 2000
#define BW_I 1000
#define NSUB 8
#define SUBCAP 8192

typedef _Float16 half4 __attribute__((ext_vector_type(4)));

// Pass A: stream edges once; append (dest,e) records to per-(bucket,class) sub-arrays.
// Appends are cursor-sequential and each sub-array is written by ONE class of blocks
// (blockIdx&7) -> cache lines fill contiguously, no cross-XCD bouncing.
__global__ __launch_bounds__(256) void bucket_k(const int* __restrict__ eu, const int* __restrict__ ei,
                                                int* __restrict__ bcur,
                                                unsigned long long* __restrict__ bent) {
  int c = blockIdx.x & 7;
  int idx = blockIdx.x * 256 + threadIdx.x;
  int stride = gridDim.x * 256;
  for (int e = idx; e < NE; e += stride) {
    int u = eu[e];
    int b0 = u / BW_U;                       // 0..49
    int p0 = atomicAdd(&bcur[b0 * NSUB + c], 1);
    if (p0 < SUBCAP)
      bent[((size_t)(b0 * NSUB + c)) * SUBCAP + p0] =
          ((unsigned long long)(unsigned)u << 32) | (unsigned)e;
    int iv = ei[e];
    int b1 = 50 + iv / BW_I;                 // 50..99
    int p1 = atomicAdd(&bcur[b1 * NSUB + c], 1);
    if (p1 < SUBCAP)
      bent[((size_t)(b1 * NSUB + c)) * SUBCAP + p1] =
          ((unsigned long long)(unsigned)(NU + iv) << 32) | (unsigned)e;
  }
}

// Pass B1: count from bucket records. cnt window per bucket <= 8 KB, reads sequential.
__global__ __launch_bounds__(256) void bcount_k(const int* __restrict__ bcur,
                                                const unsigned long long* __restrict__ bent,
                                                int* __restrict__ cnt) {
  int b = blockIdx.x % NBUCK;
  int s = blockIdx.x / NBUCK;   // 0..7: sub-array
  int n = bcur[b * NSUB + s];
  if (n > SUBCAP) n = SUBCAP;
  const unsigned long long* src = bent + ((size_t)(b * NSUB + s)) * SUBCAP;
  for (int j = threadIdx.x; j < n; j += 256) {
    int dest = (int)(src[j] >> 32);
    atomicAdd(&cnt[dest], 1);
  }
}

// Pass B2: place edge ids. eid window per bucket ~210 KB (L2-resident; the bucket
// records are the only read stream and they're tiny/sequential -- no evictor).
__global__ __launch_bounds__(256) void place_k(const int* __restrict__ bcur,
                                               const unsigned long long* __restrict__ bent,
                                               int* __restrict__ cursor, int* __restrict__ eid) {
  int b = blockIdx.x % NBUCK;
  int s = blockIdx.x / NBUCK;
  int n = bcur[b * NSUB + s];
  if (n > SUBCAP) n = SUBCAP;
  const unsigned long long* src = bent + ((size_t)(b * NSUB + s)) * SUBCAP;
  for (int j = threadIdx.x; j < n; j += 256) {
    unsigned long long v = src[j];
    int dest = (int)(v >> 32);
    int e = (int)(unsigned)v;
    int p = atomicAdd(&cursor[dest], 1);
    eid[p] = e;
  }
}

__global__ __launch_bounds__(1024) void scanA_k(const int* __restrict__ cnt, int* __restrict__ lexcl,
                                                int* __restrict__ partials, int n) {
  int idx = blockIdx.x * 1024 + threadIdx.x;
  int v = (idx < n) ? cnt[idx] : 0;
  int lane = threadIdx.x & 63;
  int wid = threadIdx.x >> 6;
  int x = v;
#pragma unroll
  for (int off = 1; off < 64; off <<= 1) {
    int y = __shfl_up(x, off, 64);
    if (lane >= off) x += y;
  }
  __shared__ int wtot[16], woff[16];
  if (lane == 63) wtot[wid] = x;
  __syncthreads();
  if (threadIdx.x == 0) {
    int a = 0;
#pragma unroll
    for (int w = 0; w < 16; ++w) { woff[w] = a; a += wtot[w]; }
    partials[blockIdx.x] = a;
  }
  __syncthreads();
  if (idx < n) lexcl[idx] = x - v + woff[wid];
}

__global__ __launch_bounds__(64) void scanB_k(int* __restrict__ partials, int* __restrict__ row, int nchunks) {
  int lane = threadIdx.x;
  int carry = 0;
  for (int base = 0; base < nchunks; base += 64) {
    int idx = base + lane;
    int v = (idx < nchunks) ? partials[idx] : 0;
    int x = v;
#pragma unroll
    for (int off = 1; off < 64; off <<= 1) {
      int y = __shfl_up(x, off, 64);
      if (lane >= off) x += y;
    }
    if (idx < nchunks) partials[idx] = carry + x - v;
    carry += __shfl(x, 63, 64);
  }
  if (lane == 0) row[NT] = carry;
}

__global__ __launch_bounds__(1024) void scanC_k(int* __restrict__ row, int* __restrict__ cursor,
                                                float* __restrict__ coef, const int* __restrict__ partials, int n) {
  int idx = blockIdx.x * 1024 + threadIdx.x;
  if (idx >= n) return;
  int c = cursor[idx];  // raw count
  int fin = row[idx] + partials[blockIdx.x];
  row[idx] = fin;
  cursor[idx] = fin;
  coef[idx] = (float)pow((double)(c > 0 ? c : 1), -0.5);
}

// Rank-sort each segment by edge id -> col in exact edge order (deterministic).
__global__ __launch_bounds__(256) void sort_k(const int* __restrict__ row, const int* __restrict__ eid,
                                              const int* __restrict__ eu, const int* __restrict__ ei,
                                              int* __restrict__ col) {
  int wv = (blockIdx.x * blockDim.x + threadIdx.x) >> 6;
  int lane = threadIdx.x & 63;
  if (wv >= NT) return;
  int beg = row[wv], end = row[wv + 1];
  for (int idx = beg + lane; idx < end; idx += 64) {
    int my = eid[idx];
    int r = 0;
    for (int j = beg; j < end; ++j) r += (eid[j] < my);
    col[beg + r] = (wv < NU) ? (NU + ei[my]) : eu[my];
  }
}

// GCN layer: 4 nodes/wave, 16 lanes x float4 dims, depth-4+4 chunked gather pipeline
// (fetch-bound at ~160us/pass: 466 MB L2-fill traffic @ ~3.5 TB/s). Arithmetic
// bit-identical: per-dim strict edge-order sum, separate mul/add rounding; noise
// pairwise-sum + fixed tree. FIRST=1: gather straight from ue/ie + init acc.
// LAST=1: fused layer mean -> out (f32) AND h16out (fp16 copy for RF gathers).
template <int FIRST, int LAST>
__global__ __launch_bounds__(256) void gcn4_k(const float* __restrict__ in, float* __restrict__ out,
                                              float* __restrict__ acc,
                                              const int* __restrict__ row, const int* __restrict__ col,
                                              const float* __restrict__ coef, const float* __restrict__ nz_l,
                                              const float* __restrict__ ue, const float* __restrict__ ie,
                                              _Float16* __restrict__ h16out) {
  int wave = (blockIdx.x * blockDim.x + threadIdx.x) >> 6;
  int lane = threadIdx.x & 63;
  int g = lane >> 4, q = lane & 15;
  int node = wave * 4 + g;
  if (node >= NT) return;
  int beg = row[node], end = row[node + 1];
  float cn = coef[node];
  float sx = 0.f, sy = 0.f, sz = 0.f, sw = 0.f;

  const float* gbase;
  if (FIRST) {
    gbase = (node < NU) ? (ie - (size_t)NU * DD) : ue;  // user->item rows, item->user rows
  } else {
    gbase = in;
  }

#define GLD(dv, dc, kk) { int m_ = col[kk]; dc = coef[m_]; dv = *(const float4*)(gbase + (size_t)m_ * DD + q * 4); }
  float4 cv0, cv1, cv2, cv3;
  float cc0, cc1, cc2, cc3;
  int rem = end - beg;
  int k4end = end - (rem & 3);
  int k = beg;
  if (k < k4end) {
    GLD(cv0, cc0, k) GLD(cv1, cc1, k + 1) GLD(cv2, cc2, k + 2) GLD(cv3, cc3, k + 3)
  }
  for (; k < k4end; k += 4) {
    float4 nv0, nv1, nv2, nv3;
    float nc0, nc1, nc2, nc3;
    bool more = (k + 4) < k4end;
    if (more) {
      GLD(nv0, nc0, k + 4) GLD(nv1, nc1, k + 5) GLD(nv2, nc2, k + 6) GLD(nv3, nc3, k + 7)
    }
    {
      float w = cn * cc0;
      sx = sx + (cv0.x * w); sy = sy + (cv0.y * w); sz = sz + (cv0.z * w); sw = sw + (cv0.w * w);
    }
    {
      float w = cn * cc1;
      sx = sx + (cv1.x * w); sy = sy + (cv1.y * w); sz = sz + (cv1.z * w); sw = sw + (cv1.w * w);
    }
    {
      float w = cn * cc2;
      sx = sx + (cv2.x * w); sy = sy + (cv2.y * w); sz = sz + (cv2.z * w); sw = sw + (cv2.w * w);
    }
    {
      float w = cn * cc3;
      sx = sx + (cv3.x * w); sy = sy + (cv3.y * w); sz = sz + (cv3.z * w); sw = sw + (cv3.w * w);
    }
    if (more) {
      cv0 = nv0; cc0 = nc0; cv1 = nv1; cc1 = nc1;
      cv2 = nv2; cc2 = nc2; cv3 = nv3; cc3 = nc3;
    }
  }
  for (; k < end; ++k) {  // tail <= 3
    float4 v; float c;
    GLD(v, c, k)
    float w = cn * c;
    sx = sx + (v.x * w); sy = sy + (v.y * w); sz = sz + (v.z * w); sw = sw + (v.w * w);
  }
#undef GLD

  // Noise norm, bit-identical: r[j] = sum over k of sq[8k+j] (sequential), tree combine.
  float4 nzv = *(const float4*)(nz_l + (size_t)node * DD + q * 4);
  float4 sq;
  sq.x = nzv.x * nzv.x; sq.y = nzv.y * nzv.y;
  sq.z = nzv.z * nzv.z; sq.w = nzv.w * nzv.w;
  float rA0 = 0.f, rA1 = 0.f, rA2 = 0.f, rA3 = 0.f;
  float rB0 = 0.f, rB1 = 0.f, rB2 = 0.f, rB3 = 0.f;
  int base = g * 16;
#pragma unroll
  for (int kk = 0; kk < 8; ++kk) {
    int le = base + 2 * kk, lo = le + 1;
    rA0 = rA0 + __shfl(sq.x, le, 64);
    rA1 = rA1 + __shfl(sq.y, le, 64);
    rA2 = rA2 + __shfl(sq.z, le, 64);
    rA3 = rA3 + __shfl(sq.w, le, 64);
    rB0 = rB0 + __shfl(sq.x, lo, 64);
    rB1 = rB1 + __shfl(sq.y, lo, 64);
    rB2 = rB2 + __shfl(sq.z, lo, 64);
    rB3 = rB3 + __shfl(sq.w, lo, 64);
  }
  float t01 = rA0 + rA1, t23 = rA2 + rA3;
  float t45 = rB0 + rB1, t67 = rB2 + rB3;
  float tot = (t01 + t23) + (t45 + t67);
  float nrm = __fsqrt_rn(tot);
  float den = fmaxf(nrm, 1e-12f);
  float4 o;
  {
    float nn = nzv.x / den;
    float sg = (sx > 0.f) ? 1.f : ((sx < 0.f) ? -1.f : 0.f);
    o.x = sx + ((sg * nn) * 0.2f);
  }
  {
    float nn = nzv.y / den;
    float sg = (sy > 0.f) ? 1.f : ((sy < 0.f) ? -1.f : 0.f);
    o.y = sy + ((sg * nn) * 0.2f);
  }
  {
    float nn = nzv.z / den;
    float sg = (sz > 0.f) ? 1.f : ((sz < 0.f) ? -1.f : 0.f);
    o.z = sz + ((sg * nn) * 0.2f);
  }
  {
    float nn = nzv.w / den;
    float sg = (sw > 0.f) ? 1.f : ((sw < 0.f) ? -1.f : 0.f);
    o.w = sw + ((sg * nn) * 0.2f);
  }
  size_t boff = (size_t)node * DD + q * 4;
  if (FIRST) {
    const float* ownp = (node < NU) ? (ue + (size_t)node * DD) : (ie + (size_t)(node - NU) * DD);
    float4 own = *(const float4*)(ownp + q * 4);
    *(float4*)(out + boff) = o;
    float4 a;
    a.x = own.x + o.x; a.y = own.y + o.y; a.z = own.z + o.z; a.w = own.w + o.w;
    *(float4*)(acc + boff) = a;
  } else {
    float4 a = *(const float4*)(acc + boff);
    if (LAST) {
      float4 mo;
      mo.x = (a.x + o.x) * 0.25f;
      mo.y = (a.y + o.y) * 0.25f;
      mo.z = (a.z + o.z) * 0.25f;
      mo.w = (a.w + o.w) * 0.25f;
      *(float4*)(out + boff) = mo;
      half4 hh;
      hh.x = (_Float16)mo.x; hh.y = (_Float16)mo.y;
      hh.z = (_Float16)mo.z; hh.w = (_Float16)mo.w;
      *(half4*)(h16out + boff) = hh;
    } else {
      *(float4*)(out + boff) = o;
      a.x = a.x + o.x; a.y = a.y + o.y; a.z = a.z + o.z; a.w = a.w + o.w;
      *(float4*)(acc + boff) = a;
    }
  }
}

// Fused Rankformer layer, fp16 neighbor gather (RF smooth; headroom validated r13).
// Own row e and all accumulation stay f32. WRITEH=1 emits fp16 copy for next layer.
template <int WRITEH>
__global__ __launch_bounds__(256) void rfaccum_k(const float* __restrict__ inF,
                                                 const _Float16* __restrict__ inH,
                                                 float* __restrict__ outF,
                                                 _Float16* __restrict__ outH,
                                                 const int* __restrict__ row, const int* __restrict__ col) {
  int wave = (blockIdx.x * blockDim.x + threadIdx.x) >> 6;
  int lane = threadIdx.x & 63;
  int g = lane >> 4, q = lane & 15;
  int node = wave * 4 + g;
  if (node >= NT) return;
  int beg = row[node], end = row[node + 1];
  size_t boff = (size_t)node * DD + q * 4;
  float4 e = *(const float4*)(inF + boff);
  float rx = 0.f, ry = 0.f, rz = 0.f, rw = 0.f, zacc = 0.f;

#define VLD(dv, kk) { dv = *(const half4*)(inH + (size_t)col[kk] * DD + q * 4); }
#define STEP(hv)                                                             \
  {                                                                          \
    float vx = (float)hv.x, vy = (float)hv.y, vz = (float)hv.z, vw = (float)hv.w; \
    float d = fmaf(e.x, vx, fmaf(e.y, vy, fmaf(e.z, vz, e.w * vw)));         \
    d += __shfl_xor(d, 1, 64); d += __shfl_xor(d, 2, 64);                    \
    d += __shfl_xor(d, 4, 64); d += __shfl_xor(d, 8, 64);                    \
    float p = __expf(d);                                                     \
    rx = fmaf(p, vx, rx); ry = fmaf(p, vy, ry);                              \
    rz = fmaf(p, vz, rz); rw = fmaf(p, vw, rw);                              \
    zacc = zacc + p;                                                         \
  }

  half4 cv0, cv1, cv2, cv3;
  int rem = end - beg;
  int k4end = end - (rem & 3);
  int k = beg;
  if (k < k4end) {
    VLD(cv0, k) VLD(cv1, k + 1) VLD(cv2, k + 2) VLD(cv3, k + 3)
  }
  for (; k < k4end; k += 4) {
    half4 nv0, nv1, nv2, nv3;
    bool more = (k + 4) < k4end;
    if (more) {
      VLD(nv0, k + 4) VLD(nv1, k + 5) VLD(nv2, k + 6) VLD(nv3, k + 7)
    }
    STEP(cv0) STEP(cv1) STEP(cv2) STEP(cv3)
    if (more) { cv0 = nv0; cv1 = nv1; cv2 = nv2; cv3 = nv3; }
  }
  for (; k < end; ++k) {
    half4 v;
    VLD(v, k)
    STEP(v)
  }
#undef STEP
#undef VLD

  float zi = 1.f / fmaxf(zacc, 1e-9f);
  float4 o;
  o.x = 0.5f * e.x + 0.5f * (rx * zi);
  o.y = 0.5f * e.y + 0.5f * (ry * zi);
  o.z = 0.5f * e.z + 0.5f * (rz * zi);
  o.w = 0.5f * e.w + 0.5f * (rw * zi);
  *(float4*)(outF + boff) = o;
  if (WRITEH) {
    half4 hh;
    hh.x = (_Float16)o.x; hh.y = (_Float16)o.y;
    hh.z = (_Float16)o.z; hh.w = (_Float16)o.w;
    *(half4*)(outH + boff) = hh;
  }
}

extern "C" void kernel_launch(void* const* d_in, const int* in_sizes, int n_in,
                              void* d_out, int out_size, void* d_ws, size_t ws_size,
                              hipStream_t stream) {
  const float* user_emb = (const float*)d_in[0];
  const float* item_emb = (const float*)d_in[1];
  const float* noise    = (const float*)d_in[2];
  const int*   edge_u   = (const int*)d_in[3];
  const int*   edge_i   = (const int*)d_in[4];
  float* out = (float*)d_out;

  // ws layout (~162 MB). Bucket records alias the H0/H1 region: bent is dead before
  // gcn L2 writes H0 (bucket/bcount/place/sort all complete first).
  float* embA = (float*)d_ws;                      // NTD f32
  float* embB = embA + (size_t)NTD;                // NTD f32
  float* coef = embB + (size_t)NTD;                // NT+16
  int*   row  = (int*)(coef + (NT + 16));          // NT+16
  int*   cursor = row + (NT + 16);                 // NT+16
  int*   partials = cursor + (NT + 16);            // 256
  int*   bcur = partials + 256;                    // 1024 (NBUCK*NSUB=800 used)
  int*   eidt = bcur + 1024;                       // 2E
  int*   col  = eidt + 2 * (size_t)NE;             // 2E
  unsigned long long* bent = (unsigned long long*)(col + 2 * (size_t)NE);  // 100*8*8192*8B = 52.4 MB
  _Float16* H0 = (_Float16*)bent;                  // NTD fp16 (aliases bent)
  _Float16* H1 = H0 + (size_t)NTD;                 // NTD fp16

  float* acc = out;  // layer-mean accumulator lives in d_out until the final RF pass

  const int nchunks = (NT + 1023) / 1024;

  hipMemsetAsync(cursor, 0, (size_t)NT * sizeof(int), stream);
  hipMemsetAsync(bcur, 0, 1024 * sizeof(int), stream);

  bucket_k<<<2048, 256, 0, stream>>>(edge_u, edge_i, bcur, bent);
  bcount_k<<<NBUCK * NSUB, 256, 0, stream>>>(bcur, bent, cursor);
  scanA_k<<<nchunks, 1024, 0, stream>>>(cursor, row, partials, NT);
  scanB_k<<<1, 64, 0, stream>>>(partials, row, nchunks);
  scanC_k<<<nchunks, 1024, 0, stream>>>(row, cursor, coef, partials, NT);
  place_k<<<NBUCK * NSUB, 256, 0, stream>>>(bcur, bent, cursor, eidt);

  const int gwave = (NT * 64 + 255) / 256;   // 64-lane-per-node grid (sort)
  const int g4    = (NT / 4 * 64) / 256;     // 4-node-per-wave grids = 9375

  sort_k<<<gwave, 256, 0, stream>>>(row, eidt, edge_u, edge_i, col);

  // L0 (FIRST, gathers from ue/ie, inits acc): -> embB
  gcn4_k<1, 0><<<g4, 256, 0, stream>>>(nullptr, embB, acc, row, col, coef,
                                       noise + 0 * (size_t)NTD, user_emb, item_emb, nullptr);
  // L1: embB -> embA
  gcn4_k<0, 0><<<g4, 256, 0, stream>>>(embB, embA, acc, row, col, coef,
                                       noise + 1 * (size_t)NTD, user_emb, item_emb, nullptr);
  // L2 (LAST, fused mean -> f32 embB + fp16 H0): embA -> embB
  gcn4_k<0, 1><<<g4, 256, 0, stream>>>(embA, embB, acc, row, col, coef,
                                       noise + 2 * (size_t)NTD, user_emb, item_emb, H0);

  // Fused RF layers with fp16 neighbor gathers: (embB,H0) -> (embA,H1) -> out
  rfaccum_k<1><<<g4, 256, 0, stream>>>(embB, H0, embA, H1, row, col);
  rfaccum_k<0><<<g4, 256, 0, stream>>>(embA, H1, out, nullptr, row, col);
}

// Round 18
// 983.534 us; speedup vs baseline: 2.5384x; 2.5384x over previous
//
#include <hip/hip_runtime.h>
#include <math.h>

// Force numpy-style arithmetic: no FMA contraction, no reassociation.
// RF kernels use explicit fmaf() where fusion is wanted (smooth ops).
#pragma clang fp contract(off)
#pragma clang fp reassociate(off)

#define NU 100000
#define NI 50000
#define NT 150000
#define DD 64
#define NE 2000000
#define NTD (NT * DD)

// Radix-style bucketed CSR build (r17 post-mortem: global-atomic cursors serialized;
// this version has ZERO global atomics in the reservation path).
// 200 endpoint-balanced buckets: 100 user buckets x 1000 users + 100 item buckets x 500
// items (~20000 +- 141 endpoints each). Fixed per-bucket regions of BCAP records.
#define NBUCK 200
#define BW_U 1000
#define BW_I 500
#define BCAP 25600     // region capacity; actual counts are exact, no overflow possible
#define NBLK 1024
#define CHW2 ((NE + NBLK - 1) / NBLK)   // 1954 edges per block chunk

typedef _Float16 half4 __attribute__((ext_vector_type(4)));
typedef unsigned long long u64;

// Pass 1: per-block LDS histogram over buckets -> plain store (no atomics).
__global__ __launch_bounds__(256) void histo_k(const int* __restrict__ eu, const int* __restrict__ ei,
                                               int* __restrict__ hist) {
  __shared__ int h[NBUCK];
  for (int t = threadIdx.x; t < NBUCK; t += 256) h[t] = 0;
  __syncthreads();
  int e0 = blockIdx.x * CHW2;
  int e1 = e0 + CHW2; if (e1 > NE) e1 = NE;
  for (int e = e0 + threadIdx.x; e < e1; e += 256) {
    atomicAdd(&h[eu[e] / BW_U], 1);
    atomicAdd(&h[100 + ei[e] / BW_I], 1);
  }
  __syncthreads();
  for (int t = threadIdx.x; t < NBUCK; t += 256) hist[blockIdx.x * NBUCK + t] = h[t];
}

// Pass 2: one wave per bucket -- exclusive scan over the 1024 block counts, in place
// (count -> global write base = b*BCAP + prefix). Also emits per-bucket totals.
__global__ __launch_bounds__(64) void hscan_k(int* __restrict__ hist, int* __restrict__ btot) {
  int b = blockIdx.x;
  int lane = threadIdx.x;
  int vals[16];
  int lsum = 0;
#pragma unroll
  for (int j = 0; j < 16; ++j) {
    vals[j] = hist[(lane * 16 + j) * NBUCK + b];
    lsum += vals[j];
  }
  int x = lsum;
#pragma unroll
  for (int off = 1; off < 64; off <<= 1) {
    int y = __shfl_up(x, off, 64);
    if (lane >= off) x += y;
  }
  int total = __shfl(x, 63, 64);
  int run = b * BCAP + (x - lsum);   // bucket base + exclusive block prefix
#pragma unroll
  for (int j = 0; j < 16; ++j) {
    int v = vals[j];
    hist[(lane * 16 + j) * NBUCK + b] = run;
    run += v;
  }
  if (lane == 0) btot[b] = total;
}

// Pass 3: re-read edges; write (dest,e) records into this block's exclusively
// reserved contiguous ranges (LDS cursors; no global atomics). ~20 records/bucket
// per block -> near-full line fills, write-amp ~1.2 vs direct fill's 14x.
__global__ __launch_bounds__(256) void scatter_k(const int* __restrict__ eu, const int* __restrict__ ei,
                                                 const int* __restrict__ base, u64* __restrict__ bent) {
  __shared__ int cur[NBUCK];
  for (int t = threadIdx.x; t < NBUCK; t += 256) cur[t] = base[blockIdx.x * NBUCK + t];
  __syncthreads();
  int e0 = blockIdx.x * CHW2;
  int e1 = e0 + CHW2; if (e1 > NE) e1 = NE;
  for (int e = e0 + threadIdx.x; e < e1; e += 256) {
    int u = eu[e];
    int p0 = atomicAdd(&cur[u / BW_U], 1);
    bent[p0] = ((u64)(unsigned)u << 32) | (unsigned)e;
    int iv = ei[e];
    int p1 = atomicAdd(&cur[100 + iv / BW_I], 1);
    bent[p1] = ((u64)(unsigned)(NU + iv) << 32) | (unsigned)e;
  }
}

// Pass 4a: per-node counts from bucket records. One block per bucket: the 4 KB cnt
// window is single-block/single-XCD; records are the only (sequential) read stream.
__global__ __launch_bounds__(512) void bcount_k(const int* __restrict__ btot,
                                                const u64* __restrict__ bent,
                                                int* __restrict__ cnt) {
  int b = blockIdx.x;
  int n = btot[b];
  const u64* src = bent + (size_t)b * BCAP;
  for (int j = threadIdx.x; j < n; j += 512) {
    atomicAdd(&cnt[(int)(src[j] >> 32)], 1);
  }
}

// Pass 4b: place edge ids. One block per bucket; eid window ~80-100 KB, exclusive.
__global__ __launch_bounds__(512) void place_k(const int* __restrict__ btot,
                                               const u64* __restrict__ bent,
                                               int* __restrict__ cursor, int* __restrict__ eid) {
  int b = blockIdx.x;
  int n = btot[b];
  const u64* src = bent + (size_t)b * BCAP;
  for (int j = threadIdx.x; j < n; j += 512) {
    u64 v = src[j];
    int p = atomicAdd(&cursor[(int)(v >> 32)], 1);
    eid[p] = (int)(unsigned)v;
  }
}

__global__ __launch_bounds__(1024) void scanA_k(const int* __restrict__ cnt, int* __restrict__ lexcl,
                                                int* __restrict__ partials, int n) {
  int idx = blockIdx.x * 1024 + threadIdx.x;
  int v = (idx < n) ? cnt[idx] : 0;
  int lane = threadIdx.x & 63;
  int wid = threadIdx.x >> 6;
  int x = v;
#pragma unroll
  for (int off = 1; off < 64; off <<= 1) {
    int y = __shfl_up(x, off, 64);
    if (lane >= off) x += y;
  }
  __shared__ int wtot[16], woff[16];
  if (lane == 63) wtot[wid] = x;
  __syncthreads();
  if (threadIdx.x == 0) {
    int a = 0;
#pragma unroll
    for (int w = 0; w < 16; ++w) { woff[w] = a; a += wtot[w]; }
    partials[blockIdx.x] = a;
  }
  __syncthreads();
  if (idx < n) lexcl[idx] = x - v + woff[wid];
}

__global__ __launch_bounds__(64) void scanB_k(int* __restrict__ partials, int* __restrict__ row, int nchunks) {
  int lane = threadIdx.x;
  int carry = 0;
  for (int base = 0; base < nchunks; base += 64) {
    int idx = base + lane;
    int v = (idx < nchunks) ? partials[idx] : 0;
    int x = v;
#pragma unroll
    for (int off = 1; off < 64; off <<= 1) {
      int y = __shfl_up(x, off, 64);
      if (lane >= off) x += y;
    }
    if (idx < nchunks) partials[idx] = carry + x - v;
    carry += __shfl(x, 63, 64);
  }
  if (lane == 0) row[NT] = carry;
}

__global__ __launch_bounds__(1024) void scanC_k(int* __restrict__ row, int* __restrict__ cursor,
                                                float* __restrict__ coef, const int* __restrict__ partials, int n) {
  int idx = blockIdx.x * 1024 + threadIdx.x;
  if (idx >= n) return;
  int c = cursor[idx];  // raw count
  int fin = row[idx] + partials[blockIdx.x];
  row[idx] = fin;
  cursor[idx] = fin;
  coef[idx] = (float)pow((double)(c > 0 ? c : 1), -0.5);
}

// Rank-sort each segment by edge id -> col in exact edge order (deterministic).
__global__ __launch_bounds__(256) void sort_k(const int* __restrict__ row, const int* __restrict__ eid,
                                              const int* __restrict__ eu, const int* __restrict__ ei,
                                              int* __restrict__ col) {
  int wv = (blockIdx.x * blockDim.x + threadIdx.x) >> 6;
  int lane = threadIdx.x & 63;
  if (wv >= NT) return;
  int beg = row[wv], end = row[wv + 1];
  for (int idx = beg + lane; idx < end; idx += 64) {
    int my = eid[idx];
    int r = 0;
    for (int j = beg; j < end; ++j) r += (eid[j] < my);
    col[beg + r] = (wv < NU) ? (NU + ei[my]) : eu[my];
  }
}

// GCN layer: 4 nodes/wave, 16 lanes x float4 dims, depth-4+4 chunked gather pipeline
// (fetch-bound at ~160us/pass). Arithmetic bit-identical: per-dim strict edge-order
// sum, separate mul/add rounding; noise pairwise-sum + fixed tree. FIRST=1: gather
// straight from ue/ie + init acc. LAST=1: fused layer mean -> out (f32) + fp16 copy.
template <int FIRST, int LAST>
__global__ __launch_bounds__(256) void gcn4_k(const float* __restrict__ in, float* __restrict__ out,
                                              float* __restrict__ acc,
                                              const int* __restrict__ row, const int* __restrict__ col,
                                              const float* __restrict__ coef, const float* __restrict__ nz_l,
                                              const float* __restrict__ ue, const float* __restrict__ ie,
                                              _Float16* __restrict__ h16out) {
  int wave = (blockIdx.x * blockDim.x + threadIdx.x) >> 6;
  int lane = threadIdx.x & 63;
  int g = lane >> 4, q = lane & 15;
  int node = wave * 4 + g;
  if (node >= NT) return;
  int beg = row[node], end = row[node + 1];
  float cn = coef[node];
  float sx = 0.f, sy = 0.f, sz = 0.f, sw = 0.f;

  const float* gbase;
  if (FIRST) {
    gbase = (node < NU) ? (ie - (size_t)NU * DD) : ue;  // user->item rows, item->user rows
  } else {
    gbase = in;
  }

#define GLD(dv, dc, kk) { int m_ = col[kk]; dc = coef[m_]; dv = *(const float4*)(gbase + (size_t)m_ * DD + q * 4); }
  float4 cv0, cv1, cv2, cv3;
  float cc0, cc1, cc2, cc3;
  int rem = end - beg;
  int k4end = end - (rem & 3);
  int k = beg;
  if (k < k4end) {
    GLD(cv0, cc0, k) GLD(cv1, cc1, k + 1) GLD(cv2, cc2, k + 2) GLD(cv3, cc3, k + 3)
  }
  for (; k < k4end; k += 4) {
    float4 nv0, nv1, nv2, nv3;
    float nc0, nc1, nc2, nc3;
    bool more = (k + 4) < k4end;
    if (more) {
      GLD(nv0, nc0, k + 4) GLD(nv1, nc1, k + 5) GLD(nv2, nc2, k + 6) GLD(nv3, nc3, k + 7)
    }
    {
      float w = cn * cc0;
      sx = sx + (cv0.x * w); sy = sy + (cv0.y * w); sz = sz + (cv0.z * w); sw = sw + (cv0.w * w);
    }
    {
      float w = cn * cc1;
      sx = sx + (cv1.x * w); sy = sy + (cv1.y * w); sz = sz + (cv1.z * w); sw = sw + (cv1.w * w);
    }
    {
      float w = cn * cc2;
      sx = sx + (cv2.x * w); sy = sy + (cv2.y * w); sz = sz + (cv2.z * w); sw = sw + (cv2.w * w);
    }
    {
      float w = cn * cc3;
      sx = sx + (cv3.x * w); sy = sy + (cv3.y * w); sz = sz + (cv3.z * w); sw = sw + (cv3.w * w);
    }
    if (more) {
      cv0 = nv0; cc0 = nc0; cv1 = nv1; cc1 = nc1;
      cv2 = nv2; cc2 = nc2; cv3 = nv3; cc3 = nc3;
    }
  }
  for (; k < end; ++k) {  // tail <= 3
    float4 v; float c;
    GLD(v, c, k)
    float w = cn * c;
    sx = sx + (v.x * w); sy = sy + (v.y * w); sz = sz + (v.z * w); sw = sw + (v.w * w);
  }
#undef GLD

  // Noise norm, bit-identical: r[j] = sum over k of sq[8k+j] (sequential), tree combine.
  float4 nzv = *(const float4*)(nz_l + (size_t)node * DD + q * 4);
  float4 sq;
  sq.x = nzv.x * nzv.x; sq.y = nzv.y * nzv.y;
  sq.z = nzv.z * nzv.z; sq.w = nzv.w * nzv.w;
  float rA0 = 0.f, rA1 = 0.f, rA2 = 0.f, rA3 = 0.f;
  float rB0 = 0.f, rB1 = 0.f, rB2 = 0.f, rB3 = 0.f;
  int base = g * 16;
#pragma unroll
  for (int kk = 0; kk < 8; ++kk) {
    int le = base + 2 * kk, lo = le + 1;
    rA0 = rA0 + __shfl(sq.x, le, 64);
    rA1 = rA1 + __shfl(sq.y, le, 64);
    rA2 = rA2 + __shfl(sq.z, le, 64);
    rA3 = rA3 + __shfl(sq.w, le, 64);
    rB0 = rB0 + __shfl(sq.x, lo, 64);
    rB1 = rB1 + __shfl(sq.y, lo, 64);
    rB2 = rB2 + __shfl(sq.z, lo, 64);
    rB3 = rB3 + __shfl(sq.w, lo, 64);
  }
  float t01 = rA0 + rA1, t23 = rA2 + rA3;
  float t45 = rB0 + rB1, t67 = rB2 + rB3;
  float tot = (t01 + t23) + (t45 + t67);
  float nrm = __fsqrt_rn(tot);
  float den = fmaxf(nrm, 1e-12f);
  float4 o;
  {
    float nn = nzv.x / den;
    float sg = (sx > 0.f) ? 1.f : ((sx < 0.f) ? -1.f : 0.f);
    o.x = sx + ((sg * nn) * 0.2f);
  }
  {
    float nn = nzv.y / den;
    float sg = (sy > 0.f) ? 1.f : ((sy < 0.f) ? -1.f : 0.f);
    o.y = sy + ((sg * nn) * 0.2f);
  }
  {
    float nn = nzv.z / den;
    float sg = (sz > 0.f) ? 1.f : ((sz < 0.f) ? -1.f : 0.f);
    o.z = sz + ((sg * nn) * 0.2f);
  }
  {
    float nn = nzv.w / den;
    float sg = (sw > 0.f) ? 1.f : ((sw < 0.f) ? -1.f : 0.f);
    o.w = sw + ((sg * nn) * 0.2f);
  }
  size_t boff = (size_t)node * DD + q * 4;
  if (FIRST) {
    const float* ownp = (node < NU) ? (ue + (size_t)node * DD) : (ie + (size_t)(node - NU) * DD);
    float4 own = *(const float4*)(ownp + q * 4);
    *(float4*)(out + boff) = o;
    float4 a;
    a.x = own.x + o.x; a.y = own.y + o.y; a.z = own.z + o.z; a.w = own.w + o.w;
    *(float4*)(acc + boff) = a;
  } else {
    float4 a = *(const float4*)(acc + boff);
    if (LAST) {
      float4 mo;
      mo.x = (a.x + o.x) * 0.25f;
      mo.y = (a.y + o.y) * 0.25f;
      mo.z = (a.z + o.z) * 0.25f;
      mo.w = (a.w + o.w) * 0.25f;
      *(float4*)(out + boff) = mo;
      half4 hh;
      hh.x = (_Float16)mo.x; hh.y = (_Float16)mo.y;
      hh.z = (_Float16)mo.z; hh.w = (_Float16)mo.w;
      *(half4*)(h16out + boff) = hh;
    } else {
      *(float4*)(out + boff) = o;
      a.x = a.x + o.x; a.y = a.y + o.y; a.z = a.z + o.z; a.w = a.w + o.w;
      *(float4*)(acc + boff) = a;
    }
  }
}

// Fused Rankformer layer, fp16 neighbor gather (RF smooth; headroom validated r13).
// Own row e and all accumulation stay f32. WRITEH=1 emits fp16 copy for next layer.
template <int WRITEH>
__global__ __launch_bounds__(256) void rfaccum_k(const float* __restrict__ inF,
                                                 const _Float16* __restrict__ inH,
                                                 float* __restrict__ outF,
                                                 _Float16* __restrict__ outH,
                                                 const int* __restrict__ row, const int* __restrict__ col) {
  int wave = (blockIdx.x * blockDim.x + threadIdx.x) >> 6;
  int lane = threadIdx.x & 63;
  int g = lane >> 4, q = lane & 15;
  int node = wave * 4 + g;
  if (node >= NT) return;
  int beg = row[node], end = row[node + 1];
  size_t boff = (size_t)node * DD + q * 4;
  float4 e = *(const float4*)(inF + boff);
  float rx = 0.f, ry = 0.f, rz = 0.f, rw = 0.f, zacc = 0.f;

#define VLD(dv, kk) { dv = *(const half4*)(inH + (size_t)col[kk] * DD + q * 4); }
#define STEP(hv)                                                             \
  {                                                                          \
    float vx = (float)hv.x, vy = (float)hv.y, vz = (float)hv.z, vw = (float)hv.w; \
    float d = fmaf(e.x, vx, fmaf(e.y, vy, fmaf(e.z, vz, e.w * vw)));         \
    d += __shfl_xor(d, 1, 64); d += __shfl_xor(d, 2, 64);                    \
    d += __shfl_xor(d, 4, 64); d += __shfl_xor(d, 8, 64);                    \
    float p = __expf(d);                                                     \
    rx = fmaf(p, vx, rx); ry = fmaf(p, vy, ry);                              \
    rz = fmaf(p, vz, rz); rw = fmaf(p, vw, rw);                              \
    zacc = zacc + p;                                                         \
  }

  half4 cv0, cv1, cv2, cv3;
  int rem = end - beg;
  int k4end = end - (rem & 3);
  int k = beg;
  if (k < k4end) {
    VLD(cv0, k) VLD(cv1, k + 1) VLD(cv2, k + 2) VLD(cv3, k + 3)
  }
  for (; k < k4end; k += 4) {
    half4 nv0, nv1, nv2, nv3;
    bool more = (k + 4) < k4end;
    if (more) {
      VLD(nv0, k + 4) VLD(nv1, k + 5) VLD(nv2, k + 6) VLD(nv3, k + 7)
    }
    STEP(cv0) STEP(cv1) STEP(cv2) STEP(cv3)
    if (more) { cv0 = nv0; cv1 = nv1; cv2 = nv2; cv3 = nv3; }
  }
  for (; k < end; ++k) {
    half4 v;
    VLD(v, k)
    STEP(v)
  }
#undef STEP
#undef VLD

  float zi = 1.f / fmaxf(zacc, 1e-9f);
  float4 o;
  o.x = 0.5f * e.x + 0.5f * (rx * zi);
  o.y = 0.5f * e.y + 0.5f * (ry * zi);
  o.z = 0.5f * e.z + 0.5f * (rz * zi);
  o.w = 0.5f * e.w + 0.5f * (rw * zi);
  *(float4*)(outF + boff) = o;
  if (WRITEH) {
    half4 hh;
    hh.x = (_Float16)o.x; hh.y = (_Float16)o.y;
    hh.z = (_Float16)o.z; hh.w = (_Float16)o.w;
    *(half4*)(outH + boff) = hh;
  }
}

extern "C" void kernel_launch(void* const* d_in, const int* in_sizes, int n_in,
                              void* d_out, int out_size, void* d_ws, size_t ws_size,
                              hipStream_t stream) {
  const float* user_emb = (const float*)d_in[0];
  const float* item_emb = (const float*)d_in[1];
  const float* noise    = (const float*)d_in[2];
  const int*   edge_u   = (const int*)d_in[3];
  const int*   edge_i   = (const int*)d_in[4];
  float* out = (float*)d_out;

  // ws layout (~151 MB). bent (41 MB) aliases the H0/H1 region (38.4 MB): bent is
  // dead after place_k, before gcn L2 writes H0.
  float* embA = (float*)d_ws;                      // NTD f32
  float* embB = embA + (size_t)NTD;                // NTD f32
  float* coef = embB + (size_t)NTD;                // NT+16
  int*   row  = (int*)(coef + (NT + 16));          // NT+16
  int*   cursor = row + (NT + 16);                 // NT+16
  int*   partials = cursor + (NT + 16);            // 256
  int*   btot = partials + 256;                    // 256
  int*   hist = btot + 256;                        // NBLK*NBUCK = 204800
  int*   eidt = hist + NBLK * NBUCK;               // 2E
  int*   col  = eidt + 2 * (size_t)NE;             // 2E
  u64*   bent = (u64*)(col + 2 * (size_t)NE);      // 200*25600*8B = 41.0 MB
  _Float16* H0 = (_Float16*)bent;                  // NTD fp16 (aliases bent)
  _Float16* H1 = H0 + (size_t)NTD;                 // NTD fp16

  float* acc = out;  // layer-mean accumulator lives in d_out until the final RF pass

  const int nchunks = (NT + 1023) / 1024;

  hipMemsetAsync(cursor, 0, (size_t)NT * sizeof(int), stream);

  histo_k<<<NBLK, 256, 0, stream>>>(edge_u, edge_i, hist);
  hscan_k<<<NBUCK, 64, 0, stream>>>(hist, btot);
  scatter_k<<<NBLK, 256, 0, stream>>>(edge_u, edge_i, hist, bent);
  bcount_k<<<NBUCK, 512, 0, stream>>>(btot, bent, cursor);
  scanA_k<<<nchunks, 1024, 0, stream>>>(cursor, row, partials, NT);
  scanB_k<<<1, 64, 0, stream>>>(partials, row, nchunks);
  scanC_k<<<nchunks, 1024, 0, stream>>>(row, cursor, coef, partials, NT);
  place_k<<<NBUCK, 512, 0, stream>>>(btot, bent, cursor, eidt);

  const int gwave = (NT * 64 + 255) / 256;   // 64-lane-per-node grid (sort)
  const int g4    = (NT / 4 * 64) / 256;     // 4-node-per-wave grids = 9375

  sort_k<<<gwave, 256, 0, stream>>>(row, eidt, edge_u, edge_i, col);

  // L0 (FIRST, gathers from ue/ie, inits acc): -> embB
  gcn4_k<1, 0><<<g4, 256, 0, stream>>>(nullptr, embB, acc, row, col, coef,
                                       noise + 0 * (size_t)NTD, user_emb, item_emb, nullptr);
  // L1: embB -> embA
  gcn4_k<0, 0><<<g4, 256, 0, stream>>>(embB, embA, acc, row, col, coef,
                                       noise + 1 * (size_t)NTD, user_emb, item_emb, nullptr);
  // L2 (LAST, fused mean -> f32 embB + fp16 H0): embA -> embB
  gcn4_k<0, 1><<<g4, 256, 0, stream>>>(embA, embB, acc, row, col, coef,
                                       noise + 2 * (size_t)NTD, user_emb, item_emb, H0);

  // Fused RF layers with fp16 neighbor gathers: (embB,H0) -> (embA,H1) -> out
  rfaccum_k<1><<<g4, 256, 0, stream>>>(embB, H0, embA, H1, row, col);
  rfaccum_k<0><<<g4, 256, 0, stream>>>(embA, H1, out, nullptr, row, col);
}